// Round 1
// baseline (2811.765 us; speedup 1.0000x reference)
//
#include <hip/hip_runtime.h>
#include <hip/hip_bf16.h>
#include <math.h>

// Problem constants (derived at launch from in_sizes, but these are the shapes):
//   x:    [128, 20000, 1] f32     rows/cols: [640000] i32   vals: [640000] f32
//   W_gc: [20, 10] f32  b_gc: [10]   W_fc: [200000, 10] f32  b_fc: [10]
//   out:  [128, 10] f32 (softmax probs)

#define NF 10          // feature count (gc and fc output width)
#define KCHEB 20       // Chebyshev order

// ---------------- CSR build ----------------

__global__ void init_kernel(int* counts, float* h_part, int N, int H) {
    int i = blockIdx.x * blockDim.x + threadIdx.x;
    if (i < N) counts[i] = 0;
    if (i < H) h_part[i] = 0.f;
}

__global__ void hist_kernel(const int* __restrict__ rows, int* __restrict__ counts, int E) {
    int e = blockIdx.x * blockDim.x + threadIdx.x;
    if (e < E) atomicAdd(&counts[rows[e]], 1);
}

#define SCAN_THREADS 1024
__global__ void scan_kernel(const int* __restrict__ counts, int* __restrict__ row_start,
                            int* __restrict__ cursor, int N) {
    __shared__ int sh[SCAN_THREADS];
    int t = threadIdx.x;
    int CH = (N + SCAN_THREADS - 1) / SCAN_THREADS;
    int base = t * CH;
    // pass 1: per-thread sum
    int sum = 0;
    for (int i = 0; i < CH; ++i) {
        int idx = base + i;
        sum += (idx < N) ? counts[idx] : 0;
    }
    sh[t] = sum;
    __syncthreads();
    // Hillis-Steele inclusive scan over per-thread sums
    for (int off = 1; off < SCAN_THREADS; off <<= 1) {
        int v = (t >= off) ? sh[t - off] : 0;
        __syncthreads();
        sh[t] += v;
        __syncthreads();
    }
    int run = (t == 0) ? 0 : sh[t - 1];  // exclusive prefix for this thread
    // pass 2: re-read counts, emit exclusive offsets
    for (int i = 0; i < CH; ++i) {
        int idx = base + i;
        if (idx < N) {
            int v = counts[idx];
            row_start[idx] = run;
            cursor[idx] = run;
            run += v;
        }
    }
    if (t == SCAN_THREADS - 1) row_start[N] = run;  // == E
}

__global__ void scatter_kernel(const int* __restrict__ rows, const int* __restrict__ cols,
                               const float* __restrict__ vals, int* __restrict__ cursor,
                               int* __restrict__ csr_col, float* __restrict__ csr_val, int E) {
    int e = blockIdx.x * blockDim.x + threadIdx.x;
    if (e >= E) return;
    int p = atomicAdd(&cursor[rows[e]], 1);
    csr_col[p] = cols[e];
    csr_val[p] = vals[e];
}

// ---------------- Chebyshev recursion ----------------

// T0[n*BC + bb] = x[(b0+bb)*N + n]   (reads coalesced along n; writes scattered — small)
__global__ void transpose_kernel(const float* __restrict__ x, float* __restrict__ T0,
                                 int N, int BC, int b0) {
    int idx = blockIdx.x * blockDim.x + threadIdx.x;
    if (idx >= N * BC) return;
    int n = idx % N;
    int bb = idx / N;
    T0[(size_t)n * BC + bb] = x[(size_t)(b0 + bb) * N + n];
}

// Tout[n][:] = alpha * (L @ Tin)[n][:] + beta * Tprev[n][:]
__global__ void spmm_kernel(const float* __restrict__ Tin, const float* __restrict__ Tprev,
                            float* __restrict__ Tout,
                            const int* __restrict__ row_start,
                            const int* __restrict__ csr_col, const float* __restrict__ csr_val,
                            int N, int BC, int bcShift, float alpha, float beta) {
    int tid = blockIdx.x * blockDim.x + threadIdx.x;
    int n = tid >> bcShift;
    int bb = tid & (BC - 1);
    if (n >= N) return;
    int s = row_start[n];
    int e = row_start[n + 1];
    float acc = 0.f;
    for (int i = s; i < e; ++i) {
        int c = csr_col[i];
        float v = csr_val[i];
        acc += v * Tin[(size_t)c * BC + bb];
    }
    size_t o = (size_t)n * BC + bb;
    float outv = alpha * acc;
    if (beta != 0.f) outv += beta * Tprev[o];
    Tout[o] = outv;
}

// ---------------- Fused projection + FC partial ----------------

// For each (n, b): gc[j] = relu(b_gc[j] + sum_k Xt[k][n][b]*W_gc[k][j])
//                  h[b][f] += sum_j gc[j] * W_fc[n*10+j][f]
__global__ void proj_fc_kernel(const float* __restrict__ Xt,    // [K][N][BC]
                               const float* __restrict__ W_gc,  // [K][NF]
                               const float* __restrict__ b_gc,  // [NF]
                               const float* __restrict__ W_fc,  // [N*NF][NF]
                               float* __restrict__ h_part,      // [B][NF]
                               int N, int BC, int bcShift, int b0) {
    __shared__ float sWg[KCHEB * NF];
    __shared__ float sbg[NF];
    extern __shared__ float sRed[];  // [BC * NF]
    int tid = threadIdx.x;
    if (tid < KCHEB * NF) sWg[tid] = W_gc[tid];
    if (tid < NF) sbg[tid] = b_gc[tid];
    for (int i = tid; i < BC * NF; i += blockDim.x) sRed[i] = 0.f;
    __syncthreads();

    int bb = tid & (BC - 1);
    int g = tid >> bcShift;
    int groups = blockDim.x >> bcShift;
    size_t plane = (size_t)N * BC;

    float h_loc[NF];
#pragma unroll
    for (int f = 0; f < NF; ++f) h_loc[f] = 0.f;

    for (int n = blockIdx.x * groups + g; n < N; n += gridDim.x * groups) {
        float xt[KCHEB];
        size_t base = (size_t)n * BC + bb;
#pragma unroll
        for (int k = 0; k < KCHEB; ++k) xt[k] = Xt[k * plane + base];
        const float* wrow = W_fc + (size_t)n * (NF * NF);
#pragma unroll
        for (int j = 0; j < NF; ++j) {
            float gc = sbg[j];
#pragma unroll
            for (int k = 0; k < KCHEB; ++k) gc += xt[k] * sWg[k * NF + j];
            gc = fmaxf(gc, 0.f);
#pragma unroll
            for (int f = 0; f < NF; ++f) h_loc[f] += gc * wrow[j * NF + f];
        }
    }
    // block-level reduction into LDS, then one global atomic per (bb, f) per block
#pragma unroll
    for (int f = 0; f < NF; ++f) atomicAdd(&sRed[bb * NF + f], h_loc[f]);
    __syncthreads();
    for (int i = tid; i < BC * NF; i += blockDim.x) {
        int rb = i / NF;
        int rf = i - rb * NF;
        atomicAdd(&h_part[(size_t)(b0 + rb) * NF + rf], sRed[i]);
    }
}

// ---------------- Bias + ReLU + softmax ----------------

__global__ void softmax_kernel(const float* __restrict__ h_part, const float* __restrict__ b_fc,
                               float* __restrict__ out, int B) {
    int b = blockIdx.x * blockDim.x + threadIdx.x;
    if (b >= B) return;
    float v[NF];
    float m = -1e30f;
#pragma unroll
    for (int f = 0; f < NF; ++f) {
        float t = fmaxf(h_part[b * NF + f] + b_fc[f], 0.f);
        v[f] = t;
        m = fmaxf(m, t);
    }
    float s = 0.f;
#pragma unroll
    for (int f = 0; f < NF; ++f) {
        v[f] = expf(v[f] - m);
        s += v[f];
    }
    float inv = 1.f / s;
#pragma unroll
    for (int f = 0; f < NF; ++f) out[b * NF + f] = v[f] * inv;
}

// ---------------- launch ----------------

extern "C" void kernel_launch(void* const* d_in, const int* in_sizes, int n_in,
                              void* d_out, int out_size, void* d_ws, size_t ws_size,
                              hipStream_t stream) {
    const float* x    = (const float*)d_in[0];
    const int*   rows = (const int*)d_in[1];
    const int*   cols = (const int*)d_in[2];
    const float* vals = (const float*)d_in[3];
    const float* W_gc = (const float*)d_in[4];
    const float* b_gc = (const float*)d_in[5];
    const float* W_fc = (const float*)d_in[6];
    const float* b_fc = (const float*)d_in[7];
    float* out = (float*)d_out;

    const int E = in_sizes[1];
    const int N = in_sizes[6] / (NF * NF);   // W_fc has N*10*10 elements
    const int B = in_sizes[0] / N;           // x has B*N elements
    const int K = in_sizes[4] / NF;          // == KCHEB

    // ---- workspace carve ----
    char* p = (char*)d_ws;
    int* counts   = (int*)p;  p += sizeof(int) * (size_t)N;
    int* row_start= (int*)p;  p += sizeof(int) * (size_t)(N + 1);
    int* cursor   = (int*)p;  p += sizeof(int) * (size_t)N;
    int* csr_col  = (int*)p;  p += sizeof(int) * (size_t)E;
    float* csr_val= (float*)p; p += sizeof(float) * (size_t)E;
    float* h_part = (float*)p; p += sizeof(float) * (size_t)B * NF;
    size_t fixed = (size_t)(p - (char*)d_ws);
    fixed = (fixed + 255) & ~(size_t)255;
    float* Xt = (float*)((char*)d_ws + fixed);

    // pick largest batch-chunk that fits the workspace
    int BC = (B < 128) ? B : 128;
    while (BC > 1 && fixed + (size_t)K * N * BC * sizeof(float) > ws_size) BC >>= 1;
    int bcShift = __builtin_ctz(BC);
    int nchunk = B / BC;

    // ---- CSR build (once per call; rows/cols restored pristine each call) ----
    {
        int H = B * NF;
        int cov = (N > H) ? N : H;
        init_kernel<<<(cov + 255) / 256, 256, 0, stream>>>(counts, h_part, N, H);
        hist_kernel<<<(E + 255) / 256, 256, 0, stream>>>(rows, counts, E);
        scan_kernel<<<1, SCAN_THREADS, 0, stream>>>(counts, row_start, cursor, N);
        scatter_kernel<<<(E + 255) / 256, 256, 0, stream>>>(rows, cols, vals, cursor,
                                                            csr_col, csr_val, E);
    }

    // ---- Chebyshev recursion + fused epilogue, per batch chunk ----
    size_t plane = (size_t)N * BC;
    int nbThreads = N * BC;
    for (int c = 0; c < nchunk; ++c) {
        int b0 = c * BC;
        transpose_kernel<<<(nbThreads + 255) / 256, 256, 0, stream>>>(x, Xt, N, BC, b0);
        for (int k = 1; k < K; ++k) {
            const float* Tin   = Xt + (size_t)(k - 1) * plane;
            const float* Tprev = (k >= 2) ? (Xt + (size_t)(k - 2) * plane) : (const float*)nullptr;
            float alpha = (k == 1) ? 1.f : 2.f;
            float beta  = (k == 1) ? 0.f : -1.f;
            spmm_kernel<<<(nbThreads + 255) / 256, 256, 0, stream>>>(
                Tin, Tprev, Xt + (size_t)k * plane, row_start, csr_col, csr_val,
                N, BC, bcShift, alpha, beta);
        }
        size_t redBytes = (size_t)BC * NF * sizeof(float);
        proj_fc_kernel<<<1024, 256, redBytes, stream>>>(Xt, W_gc, b_gc, W_fc, h_part,
                                                        N, BC, bcShift, b0);
    }

    softmax_kernel<<<1, 128, 0, stream>>>(h_part, b_fc, out, B);
}

// Round 2
// 2011.612 us; speedup vs baseline: 1.3978x; 1.3978x over previous
//
#include <hip/hip_runtime.h>
#include <hip/hip_bf16.h>
#include <math.h>

// Shapes: x [128,20000,1] f32; rows/cols [640000] i32; vals [640000] f32
// W_gc [20,10]; b_gc [10]; W_fc [200000,10]; b_fc [10]; out [128,10] f32.

#define NF 10
#define KCHEB 20
#define BCG 32                     // batch elements per XCD chunk
#define COFF (KCHEB * BCG)         // 640: element stride between nodes in Xt
#define GMAX 4

// ---------------- CSR build ----------------

__global__ void init_kernel(int* counts, float* h_part, int N, int H) {
    int i = blockIdx.x * blockDim.x + threadIdx.x;
    if (i < N) counts[i] = 0;
    if (i < H) h_part[i] = 0.f;
}

__global__ void hist_kernel(const int* __restrict__ rows, int* __restrict__ counts, int E) {
    int e = blockIdx.x * blockDim.x + threadIdx.x;
    if (e < E) atomicAdd(&counts[rows[e]], 1);
}

#define SCAN_THREADS 1024
__global__ void scan_kernel(const int* __restrict__ counts, int* __restrict__ row_start,
                            int* __restrict__ cursor, int N) {
    __shared__ int sh[SCAN_THREADS];
    int t = threadIdx.x;
    int CH = (N + SCAN_THREADS - 1) / SCAN_THREADS;
    int base = t * CH;
    int sum = 0;
    for (int i = 0; i < CH; ++i) {
        int idx = base + i;
        sum += (idx < N) ? counts[idx] : 0;
    }
    sh[t] = sum;
    __syncthreads();
    for (int off = 1; off < SCAN_THREADS; off <<= 1) {
        int v = (t >= off) ? sh[t - off] : 0;
        __syncthreads();
        sh[t] += v;
        __syncthreads();
    }
    int run = (t == 0) ? 0 : sh[t - 1];
    for (int i = 0; i < CH; ++i) {
        int idx = base + i;
        if (idx < N) {
            int v = counts[idx];
            row_start[idx] = run;
            cursor[idx] = run;
            run += v;
        }
    }
    if (t == SCAN_THREADS - 1) row_start[N] = run;
}

// csr_col stores PRE-SCALED element offsets: c * COFF (c < 20000 -> fits int)
__global__ void scatter_kernel(const int* __restrict__ rows, const int* __restrict__ cols,
                               const float* __restrict__ vals, int* __restrict__ cursor,
                               int* __restrict__ csr_col, float* __restrict__ csr_val, int E) {
    int e = blockIdx.x * blockDim.x + threadIdx.x;
    if (e >= E) return;
    int p = atomicAdd(&cursor[rows[e]], 1);
    csr_col[p] = cols[e] * COFF;
    csr_val[p] = vals[e];
}

// ---------------- T0 fill (tiled transpose) ----------------
// Xt layout: element (g, n, k, bb) at ((g*N + n)*COFF + k*BCG + bb)

__global__ void transpose_kernel(const float* __restrict__ x, float* __restrict__ Xt,
                                 int N, int ntiles, int b0s) {
    __shared__ float tile[BCG][65];
    int tid = threadIdx.x;
    int g = blockIdx.x / ntiles;
    int ti = blockIdx.x - g * ntiles;
    int n0 = ti * 64;
#pragma unroll
    for (int p = 0; p < 8; ++p) {
        int idx = p * 256 + tid;
        int row = idx >> 6;        // batch offset 0..31
        int col = idx & 63;        // node offset 0..63
        if (n0 + col < N)
            tile[row][col] = x[(size_t)(b0s + g * BCG + row) * N + n0 + col];
    }
    __syncthreads();
#pragma unroll
    for (int p = 0; p < 8; ++p) {
        int idx = p * 256 + tid;
        int nloc = idx >> 5;       // 0..63
        int bb = idx & (BCG - 1);
        int n = n0 + nloc;
        if (n < N)
            Xt[((size_t)g * N + n) * COFF + bb] = tile[bb][nloc];
    }
}

// ---------------- SpMM step ----------------
// thread: (chunk, n, bq) handles batch lanes bq*4..bq*4+3 via float4.
// Block = 256 thr = 32 nodes x 8 bq. XCD-aware: chunk = (blockIdx%8) >> xpcShift.

__global__ void spmm_kernel(float* __restrict__ Xt,
                            const int* __restrict__ row_start,
                            const int* __restrict__ csr_col, const float* __restrict__ csr_val,
                            int N, int xpcShift, int subsPerChunk,
                            int kIn, int kPrev, int kOut, float alpha, float beta) {
    int xcd = blockIdx.x & 7;
    int chunk = xcd >> xpcShift;
    int xpcMask = (1 << xpcShift) - 1;
    int sub = (blockIdx.x >> 3) * (1 << xpcShift) + (xcd & xpcMask);
    if (sub >= subsPerChunk) return;
    int tid = threadIdx.x;
    int ln = tid >> 3;             // node 0..31 within block
    int bq = tid & 7;              // float4 lane within batch chunk
    int n = sub * 32 + ln;
    if (n >= N) return;

    const float* base = Xt + (size_t)chunk * N * COFF;
    int s = row_start[n];
    int e = row_start[n + 1];
    int koff_in = kIn * BCG + bq * 4;
    float4 acc = make_float4(0.f, 0.f, 0.f, 0.f);
    for (int i = s; i < e; ++i) {
        int coff = csr_col[i];     // pre-scaled c*COFF
        float v = csr_val[i];
        const float4 t = *(const float4*)(base + coff + koff_in);
        acc.x += v * t.x; acc.y += v * t.y; acc.z += v * t.z; acc.w += v * t.w;
    }
    size_t nbase = (size_t)n * COFF + bq * 4;
    float4 outv;
    outv.x = alpha * acc.x; outv.y = alpha * acc.y;
    outv.z = alpha * acc.z; outv.w = alpha * acc.w;
    if (beta != 0.f) {
        const float4 pv = *(const float4*)(base + nbase + kPrev * BCG);
        outv.x += beta * pv.x; outv.y += beta * pv.y;
        outv.z += beta * pv.z; outv.w += beta * pv.w;
    }
    *(float4*)((float*)base + nbase + kOut * BCG) = outv;
}

// ---------------- Fused projection + FC partial ----------------
// Block = 256 thr = 8 nodes x 32 bb. Each thread covers all G chunks for its (n,bb).

template <int G>
__global__ void proj_fc_kernel(const float* __restrict__ Xt,
                               const float* __restrict__ W_gc,
                               const float* __restrict__ b_gc,
                               const float* __restrict__ W_fc,
                               float* __restrict__ h_part,
                               int N, int b0s) {
    __shared__ float sWg[KCHEB * NF];
    __shared__ float sbg[NF];
    __shared__ float sRed[G * BCG * NF];
    int tid = threadIdx.x;
    if (tid < KCHEB * NF) sWg[tid] = W_gc[tid];
    if (tid < NF) sbg[tid] = b_gc[tid];
    for (int i = tid; i < G * BCG * NF; i += 256) sRed[i] = 0.f;
    __syncthreads();

    int bb = tid & (BCG - 1);
    int ln = tid >> 5;             // node slot 0..7

    float h_loc[G * NF];
#pragma unroll
    for (int i = 0; i < G * NF; ++i) h_loc[i] = 0.f;

    int ngroups = (N + 7) / 8;
    for (int grp = blockIdx.x; grp < ngroups; grp += gridDim.x) {
        int n = grp * 8 + ln;
        if (n >= N) continue;
        float gc_all[G * NF];
#pragma unroll
        for (int g = 0; g < G; ++g) {
            float xt[KCHEB];
            const float* xp = Xt + ((size_t)g * N + n) * COFF + bb;
#pragma unroll
            for (int k = 0; k < KCHEB; ++k) xt[k] = xp[k * BCG];
#pragma unroll
            for (int j = 0; j < NF; ++j) {
                float gc = sbg[j];
#pragma unroll
                for (int k = 0; k < KCHEB; ++k) gc += xt[k] * sWg[k * NF + j];
                gc_all[g * NF + j] = fmaxf(gc, 0.f);
            }
        }
        const float* wrow = W_fc + (size_t)n * (NF * NF);
#pragma unroll
        for (int j = 0; j < NF; ++j) {
#pragma unroll
            for (int f = 0; f < NF; ++f) {
                float wf = wrow[j * NF + f];
#pragma unroll
                for (int g = 0; g < G; ++g) h_loc[g * NF + f] += gc_all[g * NF + j] * wf;
            }
        }
    }
#pragma unroll
    for (int g = 0; g < G; ++g)
#pragma unroll
        for (int f = 0; f < NF; ++f)
            atomicAdd(&sRed[(g * BCG + bb) * NF + f], h_loc[g * NF + f]);
    __syncthreads();
    for (int i = tid; i < G * BCG * NF; i += 256)
        atomicAdd(&h_part[(size_t)b0s * NF + i], sRed[i]);
}

// ---------------- Bias + ReLU + softmax ----------------

__global__ void softmax_kernel(const float* __restrict__ h_part, const float* __restrict__ b_fc,
                               float* __restrict__ out, int B) {
    int b = blockIdx.x * blockDim.x + threadIdx.x;
    if (b >= B) return;
    float v[NF];
    float m = -1e30f;
#pragma unroll
    for (int f = 0; f < NF; ++f) {
        float t = fmaxf(h_part[b * NF + f] + b_fc[f], 0.f);
        v[f] = t;
        m = fmaxf(m, t);
    }
    float s = 0.f;
#pragma unroll
    for (int f = 0; f < NF; ++f) { v[f] = expf(v[f] - m); s += v[f]; }
    float inv = 1.f / s;
#pragma unroll
    for (int f = 0; f < NF; ++f) out[b * NF + f] = v[f] * inv;
}

// ---------------- launch ----------------

extern "C" void kernel_launch(void* const* d_in, const int* in_sizes, int n_in,
                              void* d_out, int out_size, void* d_ws, size_t ws_size,
                              hipStream_t stream) {
    const float* x    = (const float*)d_in[0];
    const int*   rows = (const int*)d_in[1];
    const int*   cols = (const int*)d_in[2];
    const float* vals = (const float*)d_in[3];
    const float* W_gc = (const float*)d_in[4];
    const float* b_gc = (const float*)d_in[5];
    const float* W_fc = (const float*)d_in[6];
    const float* b_fc = (const float*)d_in[7];
    float* out = (float*)d_out;

    const int E = in_sizes[1];
    const int N = in_sizes[6] / (NF * NF);
    const int B = in_sizes[0] / N;
    const int K = in_sizes[4] / NF;   // == KCHEB
    (void)K;

    // ---- workspace carve ----
    char* p = (char*)d_ws;
    int* counts    = (int*)p;   p += sizeof(int) * (size_t)N;
    int* row_start = (int*)p;   p += sizeof(int) * (size_t)(N + 1);
    int* cursor    = (int*)p;   p += sizeof(int) * (size_t)N;
    int* csr_col   = (int*)p;   p += sizeof(int) * (size_t)E;
    float* csr_val = (float*)p; p += sizeof(float) * (size_t)E;
    float* h_part  = (float*)p; p += sizeof(float) * (size_t)B * NF;
    size_t fixed = (size_t)(p - (char*)d_ws);
    fixed = (fixed + 255) & ~(size_t)255;
    float* Xt = (float*)((char*)d_ws + fixed);

    // choose G chunks of 32 resident at once (G in {4,2,1} so 8/G is integer)
    size_t perChunk = (size_t)N * COFF * sizeof(float);  // 51.2 MB
    int G = (B >= 4 * BCG) ? 4 : (B >= 2 * BCG ? 2 : 1);
    while (G > 1 && fixed + (size_t)G * perChunk > ws_size) G >>= 1;
    int xpcShift = (G == 4) ? 1 : (G == 2 ? 2 : 3);
    int BT = G * BCG;
    int nsc = B / BT;                 // super-chunks over the batch

    // ---- CSR build ----
    {
        int H = B * NF;
        int cov = (N > H) ? N : H;
        init_kernel<<<(cov + 255) / 256, 256, 0, stream>>>(counts, h_part, N, H);
        hist_kernel<<<(E + 255) / 256, 256, 0, stream>>>(rows, counts, E);
        scan_kernel<<<1, SCAN_THREADS, 0, stream>>>(counts, row_start, cursor, N);
        scatter_kernel<<<(E + 255) / 256, 256, 0, stream>>>(rows, cols, vals, cursor,
                                                            csr_col, csr_val, E);
    }

    int ntiles = (N + 63) / 64;
    int subsPerChunk = (N + 31) / 32;
    int xpc = 1 << xpcShift;
    int gridSpmm = 8 * ((subsPerChunk + xpc - 1) / xpc);

    for (int c = 0; c < nsc; ++c) {
        int b0s = c * BT;
        transpose_kernel<<<G * ntiles, 256, 0, stream>>>(x, Xt, N, ntiles, b0s);
        for (int k = 1; k < KCHEB; ++k) {
            float alpha = (k == 1) ? 1.f : 2.f;
            float beta  = (k == 1) ? 0.f : -1.f;
            spmm_kernel<<<gridSpmm, 256, 0, stream>>>(
                Xt, row_start, csr_col, csr_val, N, xpcShift, subsPerChunk,
                k - 1, k - 2 < 0 ? 0 : k - 2, k, alpha, beta);
        }
        switch (G) {
            case 4: proj_fc_kernel<4><<<1024, 256, 0, stream>>>(Xt, W_gc, b_gc, W_fc, h_part, N, b0s); break;
            case 2: proj_fc_kernel<2><<<1024, 256, 0, stream>>>(Xt, W_gc, b_gc, W_fc, h_part, N, b0s); break;
            default: proj_fc_kernel<1><<<1024, 256, 0, stream>>>(Xt, W_gc, b_gc, W_fc, h_part, N, b0s); break;
        }
    }

    softmax_kernel<<<1, 128, 0, stream>>>(h_part, b_fc, out, B);
}

// Round 3
// 1280.618 us; speedup vs baseline: 2.1956x; 1.5708x over previous
//
#include <hip/hip_runtime.h>
#include <hip/hip_bf16.h>
#include <math.h>

// Shapes: x [128,20000,1] f32; rows/cols [640000] i32; vals [640000] f32
// W_gc [20,10]; b_gc [10]; W_fc [200000,10]; b_fc [10]; out [128,10] f32.

#define NF 10
#define KCHEB 20
#define BCG 32                     // batch elements per XCD chunk
#define COFF (KCHEB * BCG)         // 640: element stride between nodes in Xt

// ---------------- CSR build ----------------

__global__ void init_kernel(int* counts, float* h_part, int N, int H) {
    int i = blockIdx.x * blockDim.x + threadIdx.x;
    if (i < N) counts[i] = 0;
    if (i < H) h_part[i] = 0.f;
}

__global__ void hist_kernel(const int* __restrict__ rows, int* __restrict__ counts, int E) {
    int e = blockIdx.x * blockDim.x + threadIdx.x;
    if (e < E) atomicAdd(&counts[rows[e]], 1);
}

#define SCAN_THREADS 1024
__global__ void scan_kernel(const int* __restrict__ counts, int* __restrict__ row_start,
                            int* __restrict__ cursor, int N) {
    __shared__ int sh[SCAN_THREADS];
    int t = threadIdx.x;
    int CH = (N + SCAN_THREADS - 1) / SCAN_THREADS;
    int base = t * CH;
    int sum = 0;
    for (int i = 0; i < CH; ++i) {
        int idx = base + i;
        sum += (idx < N) ? counts[idx] : 0;
    }
    sh[t] = sum;
    __syncthreads();
    for (int off = 1; off < SCAN_THREADS; off <<= 1) {
        int v = (t >= off) ? sh[t - off] : 0;
        __syncthreads();
        sh[t] += v;
        __syncthreads();
    }
    int run = (t == 0) ? 0 : sh[t - 1];
    for (int i = 0; i < CH; ++i) {
        int idx = base + i;
        if (idx < N) {
            int v = counts[idx];
            row_start[idx] = run;
            cursor[idx] = run;
            run += v;
        }
    }
    if (t == SCAN_THREADS - 1) row_start[N] = run;
}

// csr[p] = (col*COFF, bits(val)) — one 8B load per edge in the hot loop
__global__ void scatter_kernel(const int* __restrict__ rows, const int* __restrict__ cols,
                               const float* __restrict__ vals, int* __restrict__ cursor,
                               int2* __restrict__ csr, int E) {
    int e = blockIdx.x * blockDim.x + threadIdx.x;
    if (e >= E) return;
    int p = atomicAdd(&cursor[rows[e]], 1);
    csr[p] = make_int2(cols[e] * COFF, __float_as_int(vals[e]));
}

// ---------------- T0 fill (tiled transpose) ----------------
// Xt layout: element (g, n, k, bb) at ((g*N + n)*COFF + k*BCG + bb)

__global__ void transpose_kernel(const float* __restrict__ x, float* __restrict__ Xt,
                                 int N, int ntiles, int b0s) {
    __shared__ float tile[BCG][65];
    int tid = threadIdx.x;
    int g = blockIdx.x / ntiles;
    int ti = blockIdx.x - g * ntiles;
    int n0 = ti * 64;
#pragma unroll
    for (int p = 0; p < 8; ++p) {
        int idx = p * 256 + tid;
        int row = idx >> 6;        // batch offset 0..31
        int col = idx & 63;        // node offset 0..63
        if (n0 + col < N)
            tile[row][col] = x[(size_t)(b0s + g * BCG + row) * N + n0 + col];
    }
    __syncthreads();
#pragma unroll
    for (int p = 0; p < 8; ++p) {
        int idx = p * 256 + tid;
        int nloc = idx >> 5;       // 0..63
        int bb = idx & (BCG - 1);
        int n = n0 + nloc;
        if (n < N)
            Xt[((size_t)g * N + n) * COFF + bb] = tile[bb][nloc];
    }
}

// ---------------- SpMM step ----------------
// thread: (chunk, n, bq) handles batch lanes bq*4..bq*4+3 via float4.
// Block = 256 thr = 32 nodes x 8 bq. XCD-aware: chunk = (blockIdx%8) >> xpcShift.

__global__ __launch_bounds__(256)
void spmm_kernel(float* __restrict__ Xt,
                 const int* __restrict__ row_start,
                 const int2* __restrict__ csr,
                 int N, int xpcShift, int subsPerChunk,
                 int kIn, int kPrev, int kOut, float alpha, float beta) {
    int xcd = blockIdx.x & 7;
    int chunk = xcd >> xpcShift;
    int xpcMask = (1 << xpcShift) - 1;
    int sub = (blockIdx.x >> 3) * (1 << xpcShift) + (xcd & xpcMask);
    if (sub >= subsPerChunk) return;
    int tid = threadIdx.x;
    int ln = tid >> 3;             // node 0..31 within block
    int bq = tid & 7;              // float4 lane within batch chunk
    int n = sub * 32 + ln;
    if (n >= N) return;

    float* base = Xt + (size_t)chunk * N * COFF;
    int s = row_start[n];
    int e = row_start[n + 1];
    int koff = kIn * BCG + bq * 4;
    float4 a0 = make_float4(0.f, 0.f, 0.f, 0.f);
    float4 a1 = make_float4(0.f, 0.f, 0.f, 0.f);
    int i = s;
    // unroll x4: 4 CSR loads + 4 gathers in flight per iteration
    for (; i + 4 <= e; i += 4) {
        int2 p0 = csr[i], p1 = csr[i + 1], p2 = csr[i + 2], p3 = csr[i + 3];
        const float4 t0 = *(const float4*)(base + p0.x + koff);
        const float4 t1 = *(const float4*)(base + p1.x + koff);
        const float4 t2 = *(const float4*)(base + p2.x + koff);
        const float4 t3 = *(const float4*)(base + p3.x + koff);
        float v0 = __int_as_float(p0.y), v1 = __int_as_float(p1.y);
        float v2 = __int_as_float(p2.y), v3 = __int_as_float(p3.y);
        a0.x += v0 * t0.x; a0.y += v0 * t0.y; a0.z += v0 * t0.z; a0.w += v0 * t0.w;
        a1.x += v1 * t1.x; a1.y += v1 * t1.y; a1.z += v1 * t1.z; a1.w += v1 * t1.w;
        a0.x += v2 * t2.x; a0.y += v2 * t2.y; a0.z += v2 * t2.z; a0.w += v2 * t2.w;
        a1.x += v3 * t3.x; a1.y += v3 * t3.y; a1.z += v3 * t3.z; a1.w += v3 * t3.w;
    }
    for (; i < e; ++i) {
        int2 p0 = csr[i];
        const float4 t0 = *(const float4*)(base + p0.x + koff);
        float v0 = __int_as_float(p0.y);
        a0.x += v0 * t0.x; a0.y += v0 * t0.y; a0.z += v0 * t0.z; a0.w += v0 * t0.w;
    }
    float4 acc;
    acc.x = alpha * (a0.x + a1.x); acc.y = alpha * (a0.y + a1.y);
    acc.z = alpha * (a0.z + a1.z); acc.w = alpha * (a0.w + a1.w);
    size_t nbase = (size_t)n * COFF + bq * 4;
    if (beta != 0.f) {
        const float4 pv = *(const float4*)(base + nbase + kPrev * BCG);
        acc.x += beta * pv.x; acc.y += beta * pv.y;
        acc.z += beta * pv.z; acc.w += beta * pv.w;
    }
    *(float4*)(base + nbase + kOut * BCG) = acc;
}

// ---------------- Fused projection + FC partial ----------------
// Block = 256 thr = 8 node-slots x 32 bb; ONE chunk per block (low reg pressure).
// Per-thread live state: xt[20] + h_loc[10] + gc  ->  no spills at 128 VGPR cap.

__global__ __launch_bounds__(256, 4)
void proj_fc_kernel(const float* __restrict__ Xt,
                    const float* __restrict__ W_gc,
                    const float* __restrict__ b_gc,
                    const float* __restrict__ W_fc,
                    float* __restrict__ h_part,
                    int N, int b0s, int G) {
    __shared__ float sWg[KCHEB * NF];
    __shared__ float sbg[NF];
    __shared__ float sRed[BCG * NF];
    int tid = threadIdx.x;
    if (tid < KCHEB * NF) sWg[tid] = W_gc[tid];
    if (tid < NF) sbg[tid] = b_gc[tid];
    for (int i = tid; i < BCG * NF; i += 256) sRed[i] = 0.f;
    __syncthreads();

    int g = blockIdx.x % G;          // chunk for this block
    int bidx = blockIdx.x / G;
    int nblk = gridDim.x / G;

    int bb = tid & (BCG - 1);
    int ln = tid >> 5;               // node slot 0..7

    float h_loc[NF];
#pragma unroll
    for (int f = 0; f < NF; ++f) h_loc[f] = 0.f;

    const float* chunkBase = Xt + (size_t)g * N * COFF;
    int ngroups = (N + 7) / 8;
    for (int grp = bidx; grp < ngroups; grp += nblk) {
        int n = grp * 8 + ln;
        if (n >= N) continue;
        float xt[KCHEB];
        const float* xp = chunkBase + (size_t)n * COFF + bb;
#pragma unroll
        for (int k = 0; k < KCHEB; ++k) xt[k] = xp[k * BCG];
        const float* wrow = W_fc + (size_t)n * (NF * NF);
#pragma unroll
        for (int j = 0; j < NF; ++j) {
            float gc = sbg[j];
#pragma unroll
            for (int k = 0; k < KCHEB; ++k) gc += xt[k] * sWg[k * NF + j];
            gc = fmaxf(gc, 0.f);
#pragma unroll
            for (int f = 0; f < NF; ++f) h_loc[f] += gc * wrow[j * NF + f];
        }
    }
#pragma unroll
    for (int f = 0; f < NF; ++f) atomicAdd(&sRed[bb * NF + f], h_loc[f]);
    __syncthreads();
    for (int i = tid; i < BCG * NF; i += 256)
        atomicAdd(&h_part[(size_t)(b0s + g * BCG) * NF + i], sRed[i]);
}

// ---------------- Bias + ReLU + softmax ----------------

__global__ void softmax_kernel(const float* __restrict__ h_part, const float* __restrict__ b_fc,
                               float* __restrict__ out, int B) {
    int b = blockIdx.x * blockDim.x + threadIdx.x;
    if (b >= B) return;
    float v[NF];
    float m = -1e30f;
#pragma unroll
    for (int f = 0; f < NF; ++f) {
        float t = fmaxf(h_part[b * NF + f] + b_fc[f], 0.f);
        v[f] = t;
        m = fmaxf(m, t);
    }
    float s = 0.f;
#pragma unroll
    for (int f = 0; f < NF; ++f) { v[f] = expf(v[f] - m); s += v[f]; }
    float inv = 1.f / s;
#pragma unroll
    for (int f = 0; f < NF; ++f) out[b * NF + f] = v[f] * inv;
}

// ---------------- launch ----------------

extern "C" void kernel_launch(void* const* d_in, const int* in_sizes, int n_in,
                              void* d_out, int out_size, void* d_ws, size_t ws_size,
                              hipStream_t stream) {
    const float* x    = (const float*)d_in[0];
    const int*   rows = (const int*)d_in[1];
    const int*   cols = (const int*)d_in[2];
    const float* vals = (const float*)d_in[3];
    const float* W_gc = (const float*)d_in[4];
    const float* b_gc = (const float*)d_in[5];
    const float* W_fc = (const float*)d_in[6];
    const float* b_fc = (const float*)d_in[7];
    float* out = (float*)d_out;

    const int E = in_sizes[1];
    const int N = in_sizes[6] / (NF * NF);
    const int B = in_sizes[0] / N;

    // ---- workspace carve ----
    char* p = (char*)d_ws;
    int* counts    = (int*)p;   p += sizeof(int) * (size_t)N;
    int* row_start = (int*)p;   p += sizeof(int) * (size_t)(N + 1);
    int* cursor    = (int*)p;   p += sizeof(int) * (size_t)N;
    p = (char*)(((size_t)p + 15) & ~(size_t)15);
    int2* csr      = (int2*)p;  p += sizeof(int2) * (size_t)E;
    float* h_part  = (float*)p; p += sizeof(float) * (size_t)B * NF;
    size_t fixed = (size_t)(p - (char*)d_ws);
    fixed = (fixed + 255) & ~(size_t)255;
    float* Xt = (float*)((char*)d_ws + fixed);

    // choose G chunks of 32 resident at once (G in {4,2,1})
    size_t perChunk = (size_t)N * COFF * sizeof(float);  // 51.2 MB
    int G = (B >= 4 * BCG) ? 4 : (B >= 2 * BCG ? 2 : 1);
    while (G > 1 && fixed + (size_t)G * perChunk > ws_size) G >>= 1;
    int xpcShift = (G == 4) ? 1 : (G == 2 ? 2 : 3);
    int BT = G * BCG;
    int nsc = B / BT;

    // ---- CSR build ----
    {
        int H = B * NF;
        int cov = (N > H) ? N : H;
        init_kernel<<<(cov + 255) / 256, 256, 0, stream>>>(counts, h_part, N, H);
        hist_kernel<<<(E + 255) / 256, 256, 0, stream>>>(rows, counts, E);
        scan_kernel<<<1, SCAN_THREADS, 0, stream>>>(counts, row_start, cursor, N);
        scatter_kernel<<<(E + 255) / 256, 256, 0, stream>>>(rows, cols, vals, cursor, csr, E);
    }

    int ntiles = (N + 63) / 64;
    int subsPerChunk = (N + 31) / 32;
    int xpc = 1 << xpcShift;
    int gridSpmm = 8 * ((subsPerChunk + xpc - 1) / xpc);

    for (int c = 0; c < nsc; ++c) {
        int b0s = c * BT;
        transpose_kernel<<<G * ntiles, 256, 0, stream>>>(x, Xt, N, ntiles, b0s);
        for (int k = 1; k < KCHEB; ++k) {
            float alpha = (k == 1) ? 1.f : 2.f;
            float beta  = (k == 1) ? 0.f : -1.f;
            spmm_kernel<<<gridSpmm, 256, 0, stream>>>(
                Xt, row_start, csr, N, xpcShift, subsPerChunk,
                k - 1, k - 2 < 0 ? 0 : k - 2, k, alpha, beta);
        }
        proj_fc_kernel<<<1024, 256, 0, stream>>>(Xt, W_gc, b_gc, W_fc, h_part, N, b0s, G);
    }

    softmax_kernel<<<1, 128, 0, stream>>>(h_part, b_fc, out, B);
}

// Round 4
// 831.271 us; speedup vs baseline: 3.3825x; 1.5406x over previous
//
#include <hip/hip_runtime.h>
#include <hip/hip_bf16.h>
#include <math.h>

// Shapes: x [128,20000,1] f32; rows/cols [640000] i32; vals [640000] f32
// W_gc [20,10]; b_gc [10]; W_fc [200000,10]; b_fc [10]; out [128,10] f32.

#define NF 10
#define KCHEB 20
#define BCG 32                     // batch elements per XCD chunk
#define COFF (KCHEB * BCG)         // 640: element stride between nodes in Xt

// ---------------- CSR build ----------------

__global__ void init_kernel(int* counts, float* h_part, int N, int H) {
    int i = blockIdx.x * blockDim.x + threadIdx.x;
    if (i < N) counts[i] = 0;
    if (i < H) h_part[i] = 0.f;
}

__global__ void hist_kernel(const int* __restrict__ rows, int* __restrict__ counts, int E) {
    int e = blockIdx.x * blockDim.x + threadIdx.x;
    if (e < E) atomicAdd(&counts[rows[e]], 1);
}

#define SCAN_THREADS 1024
__global__ void scan_kernel(const int* __restrict__ counts, int* __restrict__ row_start,
                            int* __restrict__ cursor, int N) {
    __shared__ int sh[SCAN_THREADS];
    int t = threadIdx.x;
    int CH = (N + SCAN_THREADS - 1) / SCAN_THREADS;
    int base = t * CH;
    int sum = 0;
    for (int i = 0; i < CH; ++i) {
        int idx = base + i;
        sum += (idx < N) ? counts[idx] : 0;
    }
    sh[t] = sum;
    __syncthreads();
    for (int off = 1; off < SCAN_THREADS; off <<= 1) {
        int v = (t >= off) ? sh[t - off] : 0;
        __syncthreads();
        sh[t] += v;
        __syncthreads();
    }
    int run = (t == 0) ? 0 : sh[t - 1];
    for (int i = 0; i < CH; ++i) {
        int idx = base + i;
        if (idx < N) {
            int v = counts[idx];
            row_start[idx] = run;
            cursor[idx] = run;
            run += v;
        }
    }
    if (t == SCAN_THREADS - 1) row_start[N] = run;
}

// csr[p] = (col*COFF, bits(val)) — one 8B load per edge in the hot loop
__global__ void scatter_kernel(const int* __restrict__ rows, const int* __restrict__ cols,
                               const float* __restrict__ vals, int* __restrict__ cursor,
                               int2* __restrict__ csr, int E) {
    int e = blockIdx.x * blockDim.x + threadIdx.x;
    if (e >= E) return;
    int p = atomicAdd(&cursor[rows[e]], 1);
    csr[p] = make_int2(cols[e] * COFF, __float_as_int(vals[e]));
}

// ---------------- T0 fill (tiled transpose) ----------------
// Xt layout: element (g, n, k, bb) at ((g*N + n)*COFF + k*BCG + bb)

__global__ void transpose_kernel(const float* __restrict__ x, float* __restrict__ Xt,
                                 int N, int ntiles, int b0s) {
    __shared__ float tile[BCG][65];
    int tid = threadIdx.x;
    int g = blockIdx.x / ntiles;
    int ti = blockIdx.x - g * ntiles;
    int n0 = ti * 64;
#pragma unroll
    for (int p = 0; p < 8; ++p) {
        int idx = p * 256 + tid;
        int row = idx >> 6;        // batch offset 0..31
        int col = idx & 63;        // node offset 0..63
        if (n0 + col < N)
            tile[row][col] = x[(size_t)(b0s + g * BCG + row) * N + n0 + col];
    }
    __syncthreads();
#pragma unroll
    for (int p = 0; p < 8; ++p) {
        int idx = p * 256 + tid;
        int nloc = idx >> 5;       // 0..63
        int bb = idx & (BCG - 1);
        int n = n0 + nloc;
        if (n < N)
            Xt[((size_t)g * N + n) * COFF + bb] = tile[bb][nloc];
    }
}

// ---------------- SpMM step ----------------
// thread: (chunk, n, bq) handles batch lanes bq*4..bq*4+3 via float4.
// Block = 256 thr = 32 nodes x 8 bq. XCD-aware: chunk = (blockIdx%8) >> xpcShift.

__global__ __launch_bounds__(256)
void spmm_kernel(float* __restrict__ Xt,
                 const int* __restrict__ row_start,
                 const int2* __restrict__ csr,
                 int N, int xpcShift, int subsPerChunk,
                 int kIn, int kPrev, int kOut, float alpha, float beta) {
    int xcd = blockIdx.x & 7;
    int chunk = xcd >> xpcShift;
    int xpcMask = (1 << xpcShift) - 1;
    int sub = (blockIdx.x >> 3) * (1 << xpcShift) + (xcd & xpcMask);
    if (sub >= subsPerChunk) return;
    int tid = threadIdx.x;
    int ln = tid >> 3;             // node 0..31 within block
    int bq = tid & 7;              // float4 lane within batch chunk
    int n = sub * 32 + ln;
    if (n >= N) return;

    float* base = Xt + (size_t)chunk * N * COFF;
    int s = row_start[n];
    int e = row_start[n + 1];
    int koff = kIn * BCG + bq * 4;
    float4 a0 = make_float4(0.f, 0.f, 0.f, 0.f);
    float4 a1 = make_float4(0.f, 0.f, 0.f, 0.f);
    int i = s;
    for (; i + 4 <= e; i += 4) {
        int2 p0 = csr[i], p1 = csr[i + 1], p2 = csr[i + 2], p3 = csr[i + 3];
        const float4 t0 = *(const float4*)(base + p0.x + koff);
        const float4 t1 = *(const float4*)(base + p1.x + koff);
        const float4 t2 = *(const float4*)(base + p2.x + koff);
        const float4 t3 = *(const float4*)(base + p3.x + koff);
        float v0 = __int_as_float(p0.y), v1 = __int_as_float(p1.y);
        float v2 = __int_as_float(p2.y), v3 = __int_as_float(p3.y);
        a0.x += v0 * t0.x; a0.y += v0 * t0.y; a0.z += v0 * t0.z; a0.w += v0 * t0.w;
        a1.x += v1 * t1.x; a1.y += v1 * t1.y; a1.z += v1 * t1.z; a1.w += v1 * t1.w;
        a0.x += v2 * t2.x; a0.y += v2 * t2.y; a0.z += v2 * t2.z; a0.w += v2 * t2.w;
        a1.x += v3 * t3.x; a1.y += v3 * t3.y; a1.z += v3 * t3.z; a1.w += v3 * t3.w;
    }
    for (; i < e; ++i) {
        int2 p0 = csr[i];
        const float4 t0 = *(const float4*)(base + p0.x + koff);
        float v0 = __int_as_float(p0.y);
        a0.x += v0 * t0.x; a0.y += v0 * t0.y; a0.z += v0 * t0.z; a0.w += v0 * t0.w;
    }
    float4 acc;
    acc.x = alpha * (a0.x + a1.x); acc.y = alpha * (a0.y + a1.y);
    acc.z = alpha * (a0.z + a1.z); acc.w = alpha * (a0.w + a1.w);
    size_t nbase = (size_t)n * COFF + bq * 4;
    if (beta != 0.f) {
        const float4 pv = *(const float4*)(base + nbase + kPrev * BCG);
        acc.x += beta * pv.x; acc.y += beta * pv.y;
        acc.z += beta * pv.z; acc.w += beta * pv.w;
    }
    *(float4*)(base + nbase + kOut * BCG) = acc;
}

// ---------------- Fused projection + FC partial ----------------
// Block = 256 thr = 8 node-slots x 32 bb; ONE chunk per block.
// Per grp-iter, the 8 nodes' W_fc rows (one contiguous 3.2 KB span) are staged
// into LDS by 200 float4 loads, then the j,f loop reads LDS (broadcast).

__global__ __launch_bounds__(256, 4)
void proj_fc_kernel(const float* __restrict__ Xt,
                    const float* __restrict__ W_gc,
                    const float* __restrict__ b_gc,
                    const float* __restrict__ W_fc,
                    float* __restrict__ h_part,
                    int N, int b0s, int G) {
    __shared__ float sWg[KCHEB * NF];
    __shared__ float sbg[NF];
    __shared__ float sRed[BCG * NF];
    __shared__ float sWf[8 * NF * NF];   // 800 floats = 8 nodes x 100
    int tid = threadIdx.x;
    if (tid < KCHEB * NF) sWg[tid] = W_gc[tid];
    if (tid < NF) sbg[tid] = b_gc[tid];
    for (int i = tid; i < BCG * NF; i += 256) sRed[i] = 0.f;
    __syncthreads();

    int g = blockIdx.x % G;          // chunk for this block
    int bidx = blockIdx.x / G;
    int nblk = gridDim.x / G;

    int bb = tid & (BCG - 1);
    int ln = tid >> 5;               // node slot 0..7

    float h_loc[NF];
#pragma unroll
    for (int f = 0; f < NF; ++f) h_loc[f] = 0.f;

    const float* chunkBase = Xt + (size_t)g * N * COFF;
    int ngroups = (N + 7) / 8;
    for (int grp = bidx; grp < ngroups; grp += nblk) {
        int n0 = grp * 8;
        // ---- stage W_fc rows for these 8 nodes (contiguous span) ----
        int lim = (N - n0 < 8 ? N - n0 : 8) * (NF * NF);  // multiple of 100
        int o = tid * 4;
        if (o < lim) {
            float4 w = *(const float4*)(W_fc + (size_t)n0 * (NF * NF) + o);
            *(float4*)(sWf + o) = w;
        }
        __syncthreads();

        int n = n0 + ln;
        if (n < N) {
            float xt[KCHEB];
            const float* xp = chunkBase + (size_t)n * COFF + bb;
#pragma unroll
            for (int k = 0; k < KCHEB; ++k) xt[k] = xp[k * BCG];
            const float* wrow = sWf + ln * (NF * NF);
#pragma unroll
            for (int j = 0; j < NF; ++j) {
                float gc = sbg[j];
#pragma unroll
                for (int k = 0; k < KCHEB; ++k) gc += xt[k] * sWg[k * NF + j];
                gc = fmaxf(gc, 0.f);
#pragma unroll
                for (int f = 0; f < NF; ++f) h_loc[f] += gc * wrow[j * NF + f];
            }
        }
        __syncthreads();   // protect sWf before next iteration's staging
    }
#pragma unroll
    for (int f = 0; f < NF; ++f) atomicAdd(&sRed[bb * NF + f], h_loc[f]);
    __syncthreads();
    for (int i = tid; i < BCG * NF; i += 256)
        atomicAdd(&h_part[(size_t)(b0s + g * BCG) * NF + i], sRed[i]);
}

// ---------------- Bias + ReLU + softmax ----------------

__global__ void softmax_kernel(const float* __restrict__ h_part, const float* __restrict__ b_fc,
                               float* __restrict__ out, int B) {
    int b = blockIdx.x * blockDim.x + threadIdx.x;
    if (b >= B) return;
    float v[NF];
    float m = -1e30f;
#pragma unroll
    for (int f = 0; f < NF; ++f) {
        float t = fmaxf(h_part[b * NF + f] + b_fc[f], 0.f);
        v[f] = t;
        m = fmaxf(m, t);
    }
    float s = 0.f;
#pragma unroll
    for (int f = 0; f < NF; ++f) { v[f] = expf(v[f] - m); s += v[f]; }
    float inv = 1.f / s;
#pragma unroll
    for (int f = 0; f < NF; ++f) out[b * NF + f] = v[f] * inv;
}

// ---------------- launch ----------------

extern "C" void kernel_launch(void* const* d_in, const int* in_sizes, int n_in,
                              void* d_out, int out_size, void* d_ws, size_t ws_size,
                              hipStream_t stream) {
    const float* x    = (const float*)d_in[0];
    const int*   rows = (const int*)d_in[1];
    const int*   cols = (const int*)d_in[2];
    const float* vals = (const float*)d_in[3];
    const float* W_gc = (const float*)d_in[4];
    const float* b_gc = (const float*)d_in[5];
    const float* W_fc = (const float*)d_in[6];
    const float* b_fc = (const float*)d_in[7];
    float* out = (float*)d_out;

    const int E = in_sizes[1];
    const int N = in_sizes[6] / (NF * NF);
    const int B = in_sizes[0] / N;

    // ---- workspace carve ----
    char* p = (char*)d_ws;
    int* counts    = (int*)p;   p += sizeof(int) * (size_t)N;
    int* row_start = (int*)p;   p += sizeof(int) * (size_t)(N + 1);
    int* cursor    = (int*)p;   p += sizeof(int) * (size_t)N;
    p = (char*)(((size_t)p + 15) & ~(size_t)15);
    int2* csr      = (int2*)p;  p += sizeof(int2) * (size_t)E;
    float* h_part  = (float*)p; p += sizeof(float) * (size_t)B * NF;
    size_t fixed = (size_t)(p - (char*)d_ws);
    fixed = (fixed + 255) & ~(size_t)255;
    float* Xt = (float*)((char*)d_ws + fixed);

    // choose G chunks of 32 resident at once (G in {4,2,1})
    size_t perChunk = (size_t)N * COFF * sizeof(float);  // 51.2 MB
    int G = (B >= 4 * BCG) ? 4 : (B >= 2 * BCG ? 2 : 1);
    while (G > 1 && fixed + (size_t)G * perChunk > ws_size) G >>= 1;
    int xpcShift = (G == 4) ? 1 : (G == 2 ? 2 : 3);
    int BT = G * BCG;
    int nsc = B / BT;

    // ---- CSR build ----
    {
        int H = B * NF;
        int cov = (N > H) ? N : H;
        init_kernel<<<(cov + 255) / 256, 256, 0, stream>>>(counts, h_part, N, H);
        hist_kernel<<<(E + 255) / 256, 256, 0, stream>>>(rows, counts, E);
        scan_kernel<<<1, SCAN_THREADS, 0, stream>>>(counts, row_start, cursor, N);
        scatter_kernel<<<(E + 255) / 256, 256, 0, stream>>>(rows, cols, vals, cursor, csr, E);
    }

    int ntiles = (N + 63) / 64;
    int subsPerChunk = (N + 31) / 32;
    int xpc = 1 << xpcShift;
    int gridSpmm = 8 * ((subsPerChunk + xpc - 1) / xpc);

    for (int c = 0; c < nsc; ++c) {
        int b0s = c * BT;
        transpose_kernel<<<G * ntiles, 256, 0, stream>>>(x, Xt, N, ntiles, b0s);
        for (int k = 1; k < KCHEB; ++k) {
            float alpha = (k == 1) ? 1.f : 2.f;
            float beta  = (k == 1) ? 0.f : -1.f;
            spmm_kernel<<<gridSpmm, 256, 0, stream>>>(
                Xt, row_start, csr, N, xpcShift, subsPerChunk,
                k - 1, k - 2 < 0 ? 0 : k - 2, k, alpha, beta);
        }
        proj_fc_kernel<<<2048, 256, 0, stream>>>(Xt, W_gc, b_gc, W_fc, h_part, N, b0s, G);
    }

    softmax_kernel<<<1, 128, 0, stream>>>(h_part, b_fc, out, B);
}